// Round 12
// baseline (76.956 us; speedup 1.0000x reference)
//
#include <hip/hip_runtime.h>
#include <hip/hip_bf16.h>
#include <math.h>

namespace {
constexpr int Bn = 4, Cin = 64, Cout = 64, Hh = 128, Ww = 128, Ho = 126, Wo = 126;
constexpr int Npix = Bn * Ho * Wo;          // 63504
constexpr int HW = Hh * Ww;                 // 16384
constexpr int PixPerImg = Ho * Wo;          // 15876
constexpr int NWG = (Npix + 63) / 64;       // 993 blocks (64 px each)
constexpr int ROWU = 68;                    // LDS row stride (uints): 64 + 4 pad
}

typedef __attribute__((ext_vector_type(8))) short bf16x8;
typedef __attribute__((ext_vector_type(4))) float f32x4;

__device__ __forceinline__ unsigned short f2bf(float f) {
    __hip_bfloat16 h = __float2bfloat16(f);
    return __builtin_bit_cast(unsigned short, h);
}
__device__ __forceinline__ float bf2f(unsigned short u) {
    unsigned int v = (unsigned int)u << 16;
    return __builtin_bit_cast(float, v);
}
__device__ __forceinline__ unsigned int f2bf_pk(float lo, float hi) {
    return (unsigned int)f2bf(lo) | ((unsigned int)f2bf(hi) << 16);
}
__device__ __forceinline__ bf16x8 mk8(unsigned int u0, unsigned int u1,
                                      unsigned int u2, unsigned int u3) {
    union { unsigned int u[4]; bf16x8 v; } x;
    x.u[0] = u0; x.u[1] = u1; x.u[2] = u2; x.u[3] = u3;
    return x.v;
}
// bijective XCD swizzle (m204): contiguous chunk of blocks per XCD
__device__ __forceinline__ int swz_block(int orig, int nwg) {
    int q = nwg >> 3, r = nwg & 7;
    int xcd = orig & 7, idx = orig >> 3;
    return (xcd < r ? xcd * (q + 1) : r * (q + 1) + (xcd - r) * q) + idx;
}

// ---------------------------------------------------------------------------
// prep: hi/lo bf16 A-fragment streams, PROVEN mapping (R6/R8).
// ---------------------------------------------------------------------------
__global__ __launch_bounds__(256) void prep_kernel(
    const float* __restrict__ w_off, const float* __restrict__ weight,
    unsigned short* __restrict__ wA_hi, unsigned short* __restrict__ wA_lo,
    unsigned short* __restrict__ wOff_hi, unsigned short* __restrict__ wOff_lo)
{
    int i = blockIdx.x * 256 + threadIdx.x;
    if (i < 36864) {
        int j = i % 8;  int t = i / 8;
        int l = t % 64; t /= 64;
        int h = t % 2;  t /= 2;
        int w = t % 4;  int k = t / 4;
        int cout = 16 * w + (l & 15);
        int cin  = 32 * h + 8 * (l >> 4) + j;
        float v = weight[cout * 576 + cin * 9 + k];
        unsigned short hi = f2bf(v);
        wA_hi[i] = hi;
        wA_lo[i] = f2bf(v - bf2f(hi));

        int o = cout;   // same index domain, zero-padded past 27
        float vo = o < 27 ? w_off[o * 576 + cin * 9 + k] : 0.f;
        unsigned short oh = f2bf(vo);
        wOff_hi[i] = oh;
        wOff_lo[i] = f2bf(vo - bf2f(oh));
    }
}

// ---------------------------------------------------------------------------
// NCHW f32 -> NHWC bf16-packed transpose:
//   xT16[(b*HW + hw)*32 + cp] = pack(bf16(x[b][2cp][hw]), bf16(x[b][2cp+1][hw]))
// ---------------------------------------------------------------------------
__global__ __launch_bounds__(256) void transpose_kernel(
    const float* __restrict__ x, unsigned int* __restrict__ xT16)
{
    __shared__ float t[64][65];
    int blk  = blockIdx.x;
    int b    = blk >> 8;                 // HW/64 = 256 chunks per image
    int hw0  = (blk & 255) * 64;
    int lane = (int)(threadIdx.x & 63);
    int w4   = (int)(threadIdx.x >> 6);  // 0..3

    const float* xb = x + b * (Cin * HW) + hw0;
#pragma unroll
    for (int i = 0; i < 16; ++i) {
        int cin = w4 * 16 + i;
        t[cin][lane] = xb[cin * HW + lane];
    }
    __syncthreads();
    unsigned int* dst = xT16 + ((size_t)b * HW + hw0) * 32;
    int px = (int)(threadIdx.x >> 2);
    int c8 = (int)(threadIdx.x & 3) * 8;
#pragma unroll
    for (int i = 0; i < 8; ++i) {
        int cp = c8 + i;
        dst[px * 32 + cp] = f2bf_pk(t[2 * cp][px], t[2 * cp + 1][px]);
    }
}

// ---------------------------------------------------------------------------
// offset conv (3x3 VALID, 64->27) via MFMA. T14 split: LOAD(k+1) issued
// before MFMA(k), LDS write after. MFMA spread over all 4 waves
// (ct = wid&1 cout-tile, 2 px-tiles per wave). Scalar LDS, stride 68.
// ---------------------------------------------------------------------------
__global__ __launch_bounds__(256, 4) void offconv_mfma(
    const unsigned int* __restrict__ xT16,
    const unsigned short* __restrict__ wOff_hi,
    const unsigned short* __restrict__ wOff_lo, float* __restrict__ A_conv)
{
    __shared__ unsigned int lds[2][32 * ROWU];   // 17.4 KB

    int wg   = swz_block(blockIdx.x, NWG);
    int wid  = __builtin_amdgcn_readfirstlane((int)(threadIdx.x >> 6));
    int lane = (int)(threadIdx.x & 63);
    int p  = wg * 64 + lane;
    int pc = p < Npix ? p : (Npix - 1);
    int b  = pc / PixPerImg;
    int r  = pc - b * PixPerImg;
    int ho = r / Wo;
    int wo = r - ho * Wo;

    const unsigned int* xb = xT16 + ((size_t)b * HW + ho * Ww + wo) * 32 + wid * 8;

    uint4 qa, qb;                       // pipeline registers
    auto LOAD = [&](int k) {
        int kh = k / 3, kw = k - 3 * kh;
        const unsigned int* base = xb + (kh * Ww + kw) * 32;
        qa = *reinterpret_cast<const uint4*>(base);
        qb = *reinterpret_cast<const uint4*>(base + 4);
    };
    auto WRITE = [&](int buf) {
        unsigned int* dst = &lds[buf][(8 * wid) * ROWU + lane];
        dst[0 * ROWU] = qa.x; dst[1 * ROWU] = qa.y;
        dst[2 * ROWU] = qa.z; dst[3 * ROWU] = qa.w;
        dst[4 * ROWU] = qb.x; dst[5 * ROWU] = qb.y;
        dst[6 * ROWU] = qb.z; dst[7 * ROWU] = qb.w;
    };

    int ct = wid & 1;          // cout tile (o 0-15 / 16-31)
    int t0 = (wid >> 1) * 2;   // first px tile
    f32x4 acc0 = {0.f, 0.f, 0.f, 0.f}, acc1 = acc0;

    LOAD(0);
    WRITE(0);
    __syncthreads();

#pragma unroll
    for (int k = 0; k < 9; ++k) {
        int cur = k & 1;
        if (k < 8) LOAD(k + 1);
        {
            const bf16x8* waH = reinterpret_cast<const bf16x8*>(
                wOff_hi + ((k * 4 + ct) * 2) * 512 + lane * 8);
            const bf16x8* waL = reinterpret_cast<const bf16x8*>(
                wOff_lo + ((k * 4 + ct) * 2) * 512 + lane * 8);
            bf16x8 a0h = waH[0], a1h = waH[64];
            bf16x8 a0l = waL[0], a1l = waL[64];
            const unsigned int* Lh = &lds[cur][0];
            int g4 = (lane >> 4) * 4;
#pragma unroll
            for (int tt = 0; tt < 2; ++tt) {
                int colp = 16 * (t0 + tt) + (lane & 15);
                bf16x8 b0 = mk8(Lh[(g4 + 0) * ROWU + colp], Lh[(g4 + 1) * ROWU + colp],
                                Lh[(g4 + 2) * ROWU + colp], Lh[(g4 + 3) * ROWU + colp]);
                bf16x8 b1 = mk8(Lh[(16 + g4 + 0) * ROWU + colp], Lh[(16 + g4 + 1) * ROWU + colp],
                                Lh[(16 + g4 + 2) * ROWU + colp], Lh[(16 + g4 + 3) * ROWU + colp]);
                f32x4& a = tt ? acc1 : acc0;
                a = __builtin_amdgcn_mfma_f32_16x16x32_bf16(a0h, b0, a, 0, 0, 0);
                a = __builtin_amdgcn_mfma_f32_16x16x32_bf16(a0l, b0, a, 0, 0, 0);
                a = __builtin_amdgcn_mfma_f32_16x16x32_bf16(a1h, b1, a, 0, 0, 0);
                a = __builtin_amdgcn_mfma_f32_16x16x32_bf16(a1l, b1, a, 0, 0, 0);
            }
        }
        if (k < 8) WRITE(cur ^ 1);
        __syncthreads();
    }

#pragma unroll
    for (int tt = 0; tt < 2; ++tt) {
        f32x4 a = tt ? acc1 : acc0;
        int p2 = wg * 64 + 16 * (t0 + tt) + (lane & 15);
        if (p2 >= Npix) continue;
#pragma unroll
        for (int rg = 0; rg < 4; ++rg) {
            int o = 16 * ct + 4 * (lane >> 4) + rg;
            if (o < 27) A_conv[o * Npix + p2] = a[rg];
        }
    }
}

// ---------------------------------------------------------------------------
// fused bilinear sample + main conv via MFMA. T14 split pipeline:
//   ISSUE(k+1): A_conv params (2-slot prefetch) + 8 uint4 gathers -> regs
//   MFMA(k)   : 32 LDS reads + 16 MFMA   (gather latency hides under this)
//   WRITE(k+1): vmcnt-wait + unpack + bilinear + 8 scalar LDS stores
// ---------------------------------------------------------------------------
__global__ __launch_bounds__(256, 4) void fused_mfma(
    const unsigned int* __restrict__ xT16, const float* __restrict__ A_conv,
    const float* __restrict__ b_off, const unsigned short* __restrict__ wA_hi,
    const unsigned short* __restrict__ wA_lo, const float* __restrict__ bias,
    float* __restrict__ out)
{
    __shared__ unsigned int lds[2][32 * ROWU];   // 17.4 KB

    int wg   = swz_block(blockIdx.x, NWG);
    int wid  = __builtin_amdgcn_readfirstlane((int)(threadIdx.x >> 6));
    int lane = (int)(threadIdx.x & 63);
    int p  = wg * 64 + lane;
    int pc = p < Npix ? p : (Npix - 1);
    int b  = pc / PixPerImg;
    int r  = pc - b * PixPerImg;
    int ho = r / Wo;
    int wo = r - ho * Wo;

    const unsigned int* xTb = xT16 + (size_t)b * HW * 32 + wid * 8;

    // pipeline registers
    float oyA, oxA, mvA, oyB, oxB, mvB;      // A_conv params, 2 slots
    uint4 q00a, q00b, q01a, q01b, q10a, q10b, q11a, q11b;
    float W00, W01, W10, W11;

    auto LD = [&](int k, float& oy, float& ox, float& mv) {
        oy = A_conv[(2 * k) * Npix + pc];
        ox = A_conv[(2 * k + 1) * Npix + pc];
        mv = A_conv[(18 + k) * Npix + pc];
    };
    auto ISSUE = [&](int k, float oy, float ox, float mv) {
        mv += b_off[18 + k];
        float ys = (float)(ho + k / 3) + oy + b_off[2 * k];
        float xs = (float)(wo + k % 3) + ox + b_off[2 * k + 1];
        float m  = 1.0f / (1.0f + expf(-mv));
        float y0f = floorf(ys), x0f = floorf(xs);
        float wy = ys - y0f, wx = xs - x0f;
        int y0 = (int)y0f, x0 = (int)x0f;
        float vy0 = (y0 >= 0  && y0 < Hh)     ? 1.f : 0.f;
        float vy1 = (y0 >= -1 && y0 < Hh - 1) ? 1.f : 0.f;
        float vx0 = (x0 >= 0  && x0 < Ww)     ? 1.f : 0.f;
        float vx1 = (x0 >= -1 && x0 < Ww - 1) ? 1.f : 0.f;
        int y0c = min(max(y0, 0), Hh - 1);
        int y1c = min(max(y0 + 1, 0), Hh - 1);
        int x0c = min(max(x0, 0), Ww - 1);
        int x1c = min(max(x0 + 1, 0), Ww - 1);
        W00 = (1.f - wy) * (1.f - wx) * m * vy0 * vx0;
        W01 = (1.f - wy) * wx         * m * vy0 * vx1;
        W10 = wy         * (1.f - wx) * m * vy1 * vx0;
        W11 = wy         * wx         * m * vy1 * vx1;
        const unsigned int* p00 = xTb + (y0c * Ww + x0c) * 32;
        const unsigned int* p01 = xTb + (y0c * Ww + x1c) * 32;
        const unsigned int* p10 = xTb + (y1c * Ww + x0c) * 32;
        const unsigned int* p11 = xTb + (y1c * Ww + x1c) * 32;
        q00a = *reinterpret_cast<const uint4*>(p00);
        q00b = *reinterpret_cast<const uint4*>(p00 + 4);
        q01a = *reinterpret_cast<const uint4*>(p01);
        q01b = *reinterpret_cast<const uint4*>(p01 + 4);
        q10a = *reinterpret_cast<const uint4*>(p10);
        q10b = *reinterpret_cast<const uint4*>(p10 + 4);
        q11a = *reinterpret_cast<const uint4*>(p11);
        q11b = *reinterpret_cast<const uint4*>(p11 + 4);
    };
    auto WRITE = [&](int buf) {
        unsigned int* dst = &lds[buf][(8 * wid) * ROWU + lane];
        auto DO = [&](unsigned int u00, unsigned int u01, unsigned int u10,
                      unsigned int u11, int j) {
            float c00a = bf2f((unsigned short)(u00 & 0xffff));
            float c00b = bf2f((unsigned short)(u00 >> 16));
            float c01a = bf2f((unsigned short)(u01 & 0xffff));
            float c01b = bf2f((unsigned short)(u01 >> 16));
            float c10a = bf2f((unsigned short)(u10 & 0xffff));
            float c10b = bf2f((unsigned short)(u10 >> 16));
            float c11a = bf2f((unsigned short)(u11 & 0xffff));
            float c11b = bf2f((unsigned short)(u11 >> 16));
            float s0 = W00 * c00a + W01 * c01a;
            s0 = fmaf(W10, c10a, s0); s0 = fmaf(W11, c11a, s0);
            float s1 = W00 * c00b + W01 * c01b;
            s1 = fmaf(W10, c10b, s1); s1 = fmaf(W11, c11b, s1);
            dst[j * ROWU] = f2bf_pk(s0, s1);
        };
        DO(q00a.x, q01a.x, q10a.x, q11a.x, 0);
        DO(q00a.y, q01a.y, q10a.y, q11a.y, 1);
        DO(q00a.z, q01a.z, q10a.z, q11a.z, 2);
        DO(q00a.w, q01a.w, q10a.w, q11a.w, 3);
        DO(q00b.x, q01b.x, q10b.x, q11b.x, 4);
        DO(q00b.y, q01b.y, q10b.y, q11b.y, 5);
        DO(q00b.z, q01b.z, q10b.z, q11b.z, 6);
        DO(q00b.w, q01b.w, q10b.w, q11b.w, 7);
    };

    f32x4 acc[4];
#pragma unroll
    for (int t = 0; t < 4; ++t) acc[t] = {0.f, 0.f, 0.f, 0.f};

    // prologue: params(0)->A, params(1)->B, gathers(0), write buf0
    LD(0, oyA, oxA, mvA);
    LD(1, oyB, oxB, mvB);
    ISSUE(0, oyA, oxA, mvA);
    WRITE(0);
    __syncthreads();

#pragma unroll
    for (int k = 0; k < 9; ++k) {
        int cur = k & 1;
        if (k < 8) {
            // params for k+1 were prefetched into slot ((k+1)&1 ? B : A)
            if ((k + 1) & 1) ISSUE(k + 1, oyB, oxB, mvB);
            else             ISSUE(k + 1, oyA, oxA, mvA);
            if (k < 7) {
                if ((k + 2) & 1) LD(k + 2, oyB, oxB, mvB);
                else             LD(k + 2, oyA, oxA, mvA);
            }
        }
        // MFMA(k) — gather latency for k+1 hides under this
        {
            const bf16x8* waH = reinterpret_cast<const bf16x8*>(
                wA_hi + ((k * 4 + wid) * 2) * 512 + lane * 8);
            const bf16x8* waL = reinterpret_cast<const bf16x8*>(
                wA_lo + ((k * 4 + wid) * 2) * 512 + lane * 8);
            bf16x8 a0h = waH[0], a1h = waH[64];
            bf16x8 a0l = waL[0], a1l = waL[64];
            const unsigned int* Lh = &lds[cur][0];
            int g4 = (lane >> 4) * 4;
#pragma unroll
            for (int t = 0; t < 4; ++t) {
                int colp = 16 * t + (lane & 15);
                bf16x8 b0 = mk8(Lh[(g4 + 0) * ROWU + colp], Lh[(g4 + 1) * ROWU + colp],
                                Lh[(g4 + 2) * ROWU + colp], Lh[(g4 + 3) * ROWU + colp]);
                bf16x8 b1 = mk8(Lh[(16 + g4 + 0) * ROWU + colp], Lh[(16 + g4 + 1) * ROWU + colp],
                                Lh[(16 + g4 + 2) * ROWU + colp], Lh[(16 + g4 + 3) * ROWU + colp]);
                acc[t] = __builtin_amdgcn_mfma_f32_16x16x32_bf16(a0h, b0, acc[t], 0, 0, 0);
                acc[t] = __builtin_amdgcn_mfma_f32_16x16x32_bf16(a0l, b0, acc[t], 0, 0, 0);
                acc[t] = __builtin_amdgcn_mfma_f32_16x16x32_bf16(a1h, b1, acc[t], 0, 0, 0);
                acc[t] = __builtin_amdgcn_mfma_f32_16x16x32_bf16(a1l, b1, acc[t], 0, 0, 0);
            }
        }
        if (k < 8) WRITE(cur ^ 1);
        __syncthreads();
    }

#pragma unroll
    for (int t = 0; t < 4; ++t) {
        int p2 = wg * 64 + 16 * t + (lane & 15);
        if (p2 >= Npix) continue;
        int b2 = p2 / PixPerImg;
        int r2 = p2 - b2 * PixPerImg;
        int ho2 = r2 / Wo;
        int wo2 = r2 - ho2 * Wo;
#pragma unroll
        for (int rg = 0; rg < 4; ++rg) {
            int cout = 16 * wid + 4 * (lane >> 4) + rg;
            float v = acc[t][rg] + bias[cout];
            out[((b2 * Cout + cout) * Ho + ho2) * Wo + wo2] = fmaxf(v, 0.f);
        }
    }
}

extern "C" void kernel_launch(void* const* d_in, const int* in_sizes, int n_in,
                              void* d_out, int out_size, void* d_ws, size_t ws_size,
                              hipStream_t stream)
{
    const float* x      = (const float*)d_in[0];
    const float* w_off  = (const float*)d_in[1];
    const float* b_off  = (const float*)d_in[2];
    const float* weight = (const float*)d_in[3];
    const float* bias   = (const float*)d_in[4];

    float* A_conv = (float*)d_ws;                               // 27*Npix f32
    unsigned int* xT16 = (unsigned int*)(A_conv + 27 * Npix);   // Bn*HW*32 uints
    unsigned short* wA_hi   = (unsigned short*)(xT16 + (size_t)Bn * HW * 32);
    unsigned short* wA_lo   = wA_hi + 36864;
    unsigned short* wOff_hi = wA_lo + 36864;
    unsigned short* wOff_lo = wOff_hi + 36864;

    prep_kernel<<<144, 256, 0, stream>>>(w_off, weight, wA_hi, wA_lo,
                                         wOff_hi, wOff_lo);
    transpose_kernel<<<Bn * (HW / 64), 256, 0, stream>>>(x, xT16);
    offconv_mfma<<<NWG, 256, 0, stream>>>(xT16, wOff_hi, wOff_lo, A_conv);
    fused_mfma<<<NWG, 256, 0, stream>>>(xT16, A_conv, b_off, wA_hi, wA_lo, bias,
                                        (float*)d_out);
}

// Round 13
// 67.943 us; speedup vs baseline: 1.1326x; 1.1326x over previous
//
#include <hip/hip_runtime.h>
#include <hip/hip_bf16.h>
#include <math.h>

namespace {
constexpr int Bn = 4, Cin = 64, Cout = 64, Hh = 128, Ww = 128, Ho = 126, Wo = 126;
constexpr int Npix = Bn * Ho * Wo;          // 63504
constexpr int HW = Hh * Ww;                 // 16384
constexpr int PixPerImg = Ho * Wo;          // 15876
constexpr int NWG = (Npix + 63) / 64;       // 993 blocks (64 px each)
constexpr int ROWU = 68;                    // LDS row stride (uints): 64 + 4 pad
}

typedef __attribute__((ext_vector_type(8))) short bf16x8;
typedef __attribute__((ext_vector_type(4))) float f32x4;

__device__ __forceinline__ unsigned short f2bf(float f) {
    __hip_bfloat16 h = __float2bfloat16(f);
    return __builtin_bit_cast(unsigned short, h);
}
__device__ __forceinline__ float bf2f(unsigned short u) {
    unsigned int v = (unsigned int)u << 16;
    return __builtin_bit_cast(float, v);
}
__device__ __forceinline__ unsigned int f2bf_pk(float lo, float hi) {
    return (unsigned int)f2bf(lo) | ((unsigned int)f2bf(hi) << 16);
}
__device__ __forceinline__ bf16x8 mk8(unsigned int u0, unsigned int u1,
                                      unsigned int u2, unsigned int u3) {
    union { unsigned int u[4]; bf16x8 v; } x;
    x.u[0] = u0; x.u[1] = u1; x.u[2] = u2; x.u[3] = u3;
    return x.v;
}
// bijective XCD swizzle (m204): contiguous chunk of blocks per XCD
__device__ __forceinline__ int swz_block(int orig, int nwg) {
    int q = nwg >> 3, r = nwg & 7;
    int xcd = orig & 7, idx = orig >> 3;
    return (xcd < r ? xcd * (q + 1) : r * (q + 1) + (xcd - r) * q) + idx;
}

// ---------------------------------------------------------------------------
// prep + transpose merged. Blocks [0,1024): NCHW f32 -> NHWC bf16-packed
// transpose. Blocks [1024,1168): weight A-fragment prep (PROVEN mapping).
// ---------------------------------------------------------------------------
__global__ __launch_bounds__(256) void prep_transpose_kernel(
    const float* __restrict__ x, const float* __restrict__ w_off,
    const float* __restrict__ weight, unsigned int* __restrict__ xT16,
    unsigned short* __restrict__ wA_hi, unsigned short* __restrict__ wA_lo,
    unsigned short* __restrict__ wOff_hi, unsigned short* __restrict__ wOff_lo)
{
    int blk = blockIdx.x;
    if (blk < 1024) {
        __shared__ float t[64][65];
        int b    = blk >> 8;                 // HW/64 = 256 chunks per image
        int hw0  = (blk & 255) * 64;
        int lane = (int)(threadIdx.x & 63);
        int w4   = (int)(threadIdx.x >> 6);  // 0..3

        const float* xb = x + b * (Cin * HW) + hw0;
#pragma unroll
        for (int i = 0; i < 16; ++i) {
            int cin = w4 * 16 + i;
            t[cin][lane] = xb[cin * HW + lane];
        }
        __syncthreads();
        unsigned int* dst = xT16 + ((size_t)b * HW + hw0) * 32;
        int px = (int)(threadIdx.x >> 2);
        int c8 = (int)(threadIdx.x & 3) * 8;
#pragma unroll
        for (int i = 0; i < 8; ++i) {
            int cp = c8 + i;
            dst[px * 32 + cp] = f2bf_pk(t[2 * cp][px], t[2 * cp + 1][px]);
        }
    } else {
        int i = (blk - 1024) * 256 + (int)threadIdx.x;
        if (i < 36864) {
            int j = i % 8;  int t = i / 8;
            int l = t % 64; t /= 64;
            int h = t % 2;  t /= 2;
            int w = t % 4;  int k = t / 4;
            int cout = 16 * w + (l & 15);
            int cin  = 32 * h + 8 * (l >> 4) + j;
            float v = weight[cout * 576 + cin * 9 + k];
            unsigned short hi = f2bf(v);
            wA_hi[i] = hi;
            wA_lo[i] = f2bf(v - bf2f(hi));

            int o = cout;   // same index domain, zero-padded past 27
            float vo = o < 27 ? w_off[o * 576 + cin * 9 + k] : 0.f;
            unsigned short oh = f2bf(vo);
            wOff_hi[i] = oh;
            wOff_lo[i] = f2bf(vo - bf2f(oh));
        }
    }
}

// ---------------------------------------------------------------------------
// MERGED deformable conv kernel. Block = 64 px, 4 waves.
// Phase 0: offset conv (R11/R12-proven structure) -> Ap[27][64] in LDS.
// Phase 1: bilinear sample + main conv (R12-proven), params read from Ap.
// Scalar-uint LDS accesses only (session rule). Staging stride 68.
// ---------------------------------------------------------------------------
__global__ __launch_bounds__(256, 4) void mdcn_kernel(
    const unsigned int* __restrict__ xT16, const float* __restrict__ b_off,
    const unsigned short* __restrict__ wOff_hi,
    const unsigned short* __restrict__ wOff_lo,
    const unsigned short* __restrict__ wA_hi,
    const unsigned short* __restrict__ wA_lo,
    const float* __restrict__ bias, float* __restrict__ out)
{
    __shared__ unsigned int lds[2][32 * ROWU];   // 17408 B staging (dbuf)
    __shared__ float Ap[27][64];                 // 6912 B offset-conv output

    int wg   = swz_block(blockIdx.x, NWG);
    int wid  = __builtin_amdgcn_readfirstlane((int)(threadIdx.x >> 6));
    int lane = (int)(threadIdx.x & 63);
    int p  = wg * 64 + lane;
    int pc = p < Npix ? p : (Npix - 1);
    int b  = pc / PixPerImg;
    int r  = pc - b * PixPerImg;
    int ho = r / Wo;
    int wo = r - ho * Wo;

    // ======================= phase 0: offset conv ==========================
    {
        const unsigned int* xb =
            xT16 + ((size_t)b * HW + ho * Ww + wo) * 32 + wid * 8;

        uint4 qa, qb;
        auto LOAD = [&](int k) {
            int kh = k / 3, kw = k - 3 * kh;
            const unsigned int* base = xb + (kh * Ww + kw) * 32;
            qa = *reinterpret_cast<const uint4*>(base);
            qb = *reinterpret_cast<const uint4*>(base + 4);
        };
        auto WRITE = [&](int buf) {
            unsigned int* dst = &lds[buf][(8 * wid) * ROWU + lane];
            dst[0 * ROWU] = qa.x; dst[1 * ROWU] = qa.y;
            dst[2 * ROWU] = qa.z; dst[3 * ROWU] = qa.w;
            dst[4 * ROWU] = qb.x; dst[5 * ROWU] = qb.y;
            dst[6 * ROWU] = qb.z; dst[7 * ROWU] = qb.w;
        };

        int ct = wid & 1;          // cout tile (o 0-15 / 16-31)
        int t0 = (wid >> 1) * 2;   // first px tile
        f32x4 acc0 = {0.f, 0.f, 0.f, 0.f}, acc1 = acc0;

        LOAD(0);
        WRITE(0);
        __syncthreads();

#pragma unroll
        for (int k = 0; k < 9; ++k) {
            int cur = k & 1;
            if (k < 8) LOAD(k + 1);
            {
                const bf16x8* waH = reinterpret_cast<const bf16x8*>(
                    wOff_hi + ((k * 4 + ct) * 2) * 512 + lane * 8);
                const bf16x8* waL = reinterpret_cast<const bf16x8*>(
                    wOff_lo + ((k * 4 + ct) * 2) * 512 + lane * 8);
                bf16x8 a0h = waH[0], a1h = waH[64];
                bf16x8 a0l = waL[0], a1l = waL[64];
                const unsigned int* Lh = &lds[cur][0];
                int g4 = (lane >> 4) * 4;
#pragma unroll
                for (int tt = 0; tt < 2; ++tt) {
                    int colp = 16 * (t0 + tt) + (lane & 15);
                    bf16x8 b0 = mk8(Lh[(g4 + 0) * ROWU + colp], Lh[(g4 + 1) * ROWU + colp],
                                    Lh[(g4 + 2) * ROWU + colp], Lh[(g4 + 3) * ROWU + colp]);
                    bf16x8 b1 = mk8(Lh[(16 + g4 + 0) * ROWU + colp], Lh[(16 + g4 + 1) * ROWU + colp],
                                    Lh[(16 + g4 + 2) * ROWU + colp], Lh[(16 + g4 + 3) * ROWU + colp]);
                    f32x4& a = tt ? acc1 : acc0;
                    a = __builtin_amdgcn_mfma_f32_16x16x32_bf16(a0h, b0, a, 0, 0, 0);
                    a = __builtin_amdgcn_mfma_f32_16x16x32_bf16(a0l, b0, a, 0, 0, 0);
                    a = __builtin_amdgcn_mfma_f32_16x16x32_bf16(a1h, b1, a, 0, 0, 0);
                    a = __builtin_amdgcn_mfma_f32_16x16x32_bf16(a1l, b1, a, 0, 0, 0);
                }
            }
            if (k < 8) WRITE(cur ^ 1);
            __syncthreads();
        }

        // epilogue -> Ap planes (LDS, no Npix guard needed)
#pragma unroll
        for (int tt = 0; tt < 2; ++tt) {
            f32x4 a = tt ? acc1 : acc0;
            int px = 16 * (t0 + tt) + (lane & 15);
#pragma unroll
            for (int rg = 0; rg < 4; ++rg) {
                int o = 16 * ct + 4 * (lane >> 4) + rg;
                if (o < 27) Ap[o][px] = a[rg];
            }
        }
        __syncthreads();
    }

    // ======================= phase 1: sample + main conv ===================
    const unsigned int* xTb = xT16 + (size_t)b * HW * 32 + wid * 8;

    uint4 q00a, q00b, q01a, q01b, q10a, q10b, q11a, q11b;
    float W00, W01, W10, W11;

    auto ISSUE = [&](int k) {
        float oy = Ap[2 * k][lane];
        float ox = Ap[2 * k + 1][lane];
        float mv = Ap[18 + k][lane] + b_off[18 + k];
        float ys = (float)(ho + k / 3) + oy + b_off[2 * k];
        float xs = (float)(wo + k % 3) + ox + b_off[2 * k + 1];
        float m  = 1.0f / (1.0f + expf(-mv));
        float y0f = floorf(ys), x0f = floorf(xs);
        float wy = ys - y0f, wx = xs - x0f;
        int y0 = (int)y0f, x0 = (int)x0f;
        float vy0 = (y0 >= 0  && y0 < Hh)     ? 1.f : 0.f;
        float vy1 = (y0 >= -1 && y0 < Hh - 1) ? 1.f : 0.f;
        float vx0 = (x0 >= 0  && x0 < Ww)     ? 1.f : 0.f;
        float vx1 = (x0 >= -1 && x0 < Ww - 1) ? 1.f : 0.f;
        int y0c = min(max(y0, 0), Hh - 1);
        int y1c = min(max(y0 + 1, 0), Hh - 1);
        int x0c = min(max(x0, 0), Ww - 1);
        int x1c = min(max(x0 + 1, 0), Ww - 1);
        W00 = (1.f - wy) * (1.f - wx) * m * vy0 * vx0;
        W01 = (1.f - wy) * wx         * m * vy0 * vx1;
        W10 = wy         * (1.f - wx) * m * vy1 * vx0;
        W11 = wy         * wx         * m * vy1 * vx1;
        const unsigned int* p00 = xTb + (y0c * Ww + x0c) * 32;
        const unsigned int* p01 = xTb + (y0c * Ww + x1c) * 32;
        const unsigned int* p10 = xTb + (y1c * Ww + x0c) * 32;
        const unsigned int* p11 = xTb + (y1c * Ww + x1c) * 32;
        q00a = *reinterpret_cast<const uint4*>(p00);
        q00b = *reinterpret_cast<const uint4*>(p00 + 4);
        q01a = *reinterpret_cast<const uint4*>(p01);
        q01b = *reinterpret_cast<const uint4*>(p01 + 4);
        q10a = *reinterpret_cast<const uint4*>(p10);
        q10b = *reinterpret_cast<const uint4*>(p10 + 4);
        q11a = *reinterpret_cast<const uint4*>(p11);
        q11b = *reinterpret_cast<const uint4*>(p11 + 4);
    };
    auto WRITE1 = [&](int buf) {
        unsigned int* dst = &lds[buf][(8 * wid) * ROWU + lane];
        auto DO = [&](unsigned int u00, unsigned int u01, unsigned int u10,
                      unsigned int u11, int j) {
            float c00a = bf2f((unsigned short)(u00 & 0xffff));
            float c00b = bf2f((unsigned short)(u00 >> 16));
            float c01a = bf2f((unsigned short)(u01 & 0xffff));
            float c01b = bf2f((unsigned short)(u01 >> 16));
            float c10a = bf2f((unsigned short)(u10 & 0xffff));
            float c10b = bf2f((unsigned short)(u10 >> 16));
            float c11a = bf2f((unsigned short)(u11 & 0xffff));
            float c11b = bf2f((unsigned short)(u11 >> 16));
            float s0 = W00 * c00a + W01 * c01a;
            s0 = fmaf(W10, c10a, s0); s0 = fmaf(W11, c11a, s0);
            float s1 = W00 * c00b + W01 * c01b;
            s1 = fmaf(W10, c10b, s1); s1 = fmaf(W11, c11b, s1);
            dst[j * ROWU] = f2bf_pk(s0, s1);
        };
        DO(q00a.x, q01a.x, q10a.x, q11a.x, 0);
        DO(q00a.y, q01a.y, q10a.y, q11a.y, 1);
        DO(q00a.z, q01a.z, q10a.z, q11a.z, 2);
        DO(q00a.w, q01a.w, q10a.w, q11a.w, 3);
        DO(q00b.x, q01b.x, q10b.x, q11b.x, 4);
        DO(q00b.y, q01b.y, q10b.y, q11b.y, 5);
        DO(q00b.z, q01b.z, q10b.z, q11b.z, 6);
        DO(q00b.w, q01b.w, q10b.w, q11b.w, 7);
    };

    f32x4 acc[4];
#pragma unroll
    for (int t = 0; t < 4; ++t) acc[t] = {0.f, 0.f, 0.f, 0.f};

    ISSUE(0);
    WRITE1(0);
    __syncthreads();

#pragma unroll
    for (int k = 0; k < 9; ++k) {
        int cur = k & 1;
        if (k < 8) ISSUE(k + 1);   // gathers in flight during MFMA(k)
        {
            const bf16x8* waH = reinterpret_cast<const bf16x8*>(
                wA_hi + ((k * 4 + wid) * 2) * 512 + lane * 8);
            const bf16x8* waL = reinterpret_cast<const bf16x8*>(
                wA_lo + ((k * 4 + wid) * 2) * 512 + lane * 8);
            bf16x8 a0h = waH[0], a1h = waH[64];
            bf16x8 a0l = waL[0], a1l = waL[64];
            const unsigned int* Lh = &lds[cur][0];
            int g4 = (lane >> 4) * 4;
#pragma unroll
            for (int t = 0; t < 4; ++t) {
                int colp = 16 * t + (lane & 15);
                bf16x8 b0 = mk8(Lh[(g4 + 0) * ROWU + colp], Lh[(g4 + 1) * ROWU + colp],
                                Lh[(g4 + 2) * ROWU + colp], Lh[(g4 + 3) * ROWU + colp]);
                bf16x8 b1 = mk8(Lh[(16 + g4 + 0) * ROWU + colp], Lh[(16 + g4 + 1) * ROWU + colp],
                                Lh[(16 + g4 + 2) * ROWU + colp], Lh[(16 + g4 + 3) * ROWU + colp]);
                acc[t] = __builtin_amdgcn_mfma_f32_16x16x32_bf16(a0h, b0, acc[t], 0, 0, 0);
                acc[t] = __builtin_amdgcn_mfma_f32_16x16x32_bf16(a0l, b0, acc[t], 0, 0, 0);
                acc[t] = __builtin_amdgcn_mfma_f32_16x16x32_bf16(a1h, b1, acc[t], 0, 0, 0);
                acc[t] = __builtin_amdgcn_mfma_f32_16x16x32_bf16(a1l, b1, acc[t], 0, 0, 0);
            }
        }
        if (k < 8) WRITE1(cur ^ 1);
        __syncthreads();
    }

#pragma unroll
    for (int t = 0; t < 4; ++t) {
        int p2 = wg * 64 + 16 * t + (lane & 15);
        if (p2 >= Npix) continue;
        int b2 = p2 / PixPerImg;
        int r2 = p2 - b2 * PixPerImg;
        int ho2 = r2 / Wo;
        int wo2 = r2 - ho2 * Wo;
#pragma unroll
        for (int rg = 0; rg < 4; ++rg) {
            int cout = 16 * wid + 4 * (lane >> 4) + rg;
            float v = acc[t][rg] + bias[cout];
            out[((b2 * Cout + cout) * Ho + ho2) * Wo + wo2] = fmaxf(v, 0.f);
        }
    }
}

extern "C" void kernel_launch(void* const* d_in, const int* in_sizes, int n_in,
                              void* d_out, int out_size, void* d_ws, size_t ws_size,
                              hipStream_t stream)
{
    const float* x      = (const float*)d_in[0];
    const float* w_off  = (const float*)d_in[1];
    const float* b_off  = (const float*)d_in[2];
    const float* weight = (const float*)d_in[3];
    const float* bias   = (const float*)d_in[4];

    unsigned int* xT16 = (unsigned int*)d_ws;                   // Bn*HW*32 uints
    unsigned short* wA_hi   = (unsigned short*)(xT16 + (size_t)Bn * HW * 32);
    unsigned short* wA_lo   = wA_hi + 36864;
    unsigned short* wOff_hi = wA_lo + 36864;
    unsigned short* wOff_lo = wOff_hi + 36864;

    prep_transpose_kernel<<<1024 + 144, 256, 0, stream>>>(
        x, w_off, weight, xT16, wA_hi, wA_lo, wOff_hi, wOff_lo);
    mdcn_kernel<<<NWG, 256, 0, stream>>>(xT16, b_off, wOff_hi, wOff_lo,
                                         wA_hi, wA_lo, bias, (float*)d_out);
}

// Round 14
// 57.028 us; speedup vs baseline: 1.3495x; 1.1914x over previous
//
#include <hip/hip_runtime.h>
#include <hip/hip_bf16.h>
#include <math.h>

namespace {
constexpr int Bn = 4, Cin = 64, Cout = 64, Hh = 128, Ww = 128, Ho = 126, Wo = 126;
constexpr int HW = Hh * Ww;                 // 16384
constexpr int WOB = 63;                     // pixels per block (row-aligned)
constexpr int NBLK = Bn * Ho * 2;           // 1008 blocks (63 px each, exact)
constexpr int ROWU = 68;                    // staging row stride (uints): 64+4 pad
constexpr int RSTR = 6 * 68;                // region stride per cp = 408 uints
}

typedef __attribute__((ext_vector_type(8))) short bf16x8;
typedef __attribute__((ext_vector_type(4))) float f32x4;

__device__ __forceinline__ unsigned short f2bf(float f) {
    __hip_bfloat16 h = __float2bfloat16(f);
    return __builtin_bit_cast(unsigned short, h);
}
__device__ __forceinline__ float bf2f(unsigned short u) {
    unsigned int v = (unsigned int)u << 16;
    return __builtin_bit_cast(float, v);
}
__device__ __forceinline__ unsigned int f2bf_pk(float lo, float hi) {
    return (unsigned int)f2bf(lo) | ((unsigned int)f2bf(hi) << 16);
}
__device__ __forceinline__ bf16x8 mk8(unsigned int u0, unsigned int u1,
                                      unsigned int u2, unsigned int u3) {
    union { unsigned int u[4]; bf16x8 v; } x;
    x.u[0] = u0; x.u[1] = u1; x.u[2] = u2; x.u[3] = u3;
    return x.v;
}
// bijective XCD swizzle (m204): contiguous chunk of blocks per XCD
__device__ __forceinline__ int swz_block(int orig, int nwg) {
    int q = nwg >> 3, r = nwg & 7;
    int xcd = orig & 7, idx = orig >> 3;
    return (xcd < r ? xcd * (q + 1) : r * (q + 1) + (xcd - r) * q) + idx;
}

// ---------------------------------------------------------------------------
// prep + transpose merged (R13-proven). Blocks [0,1024): NCHW f32 -> NHWC
// bf16-packed. Blocks [1024,1168): weight A-fragment prep (PROVEN mapping).
// ---------------------------------------------------------------------------
__global__ __launch_bounds__(256) void prep_transpose_kernel(
    const float* __restrict__ x, const float* __restrict__ w_off,
    const float* __restrict__ weight, unsigned int* __restrict__ xT16,
    unsigned short* __restrict__ wA_hi, unsigned short* __restrict__ wA_lo,
    unsigned short* __restrict__ wOff_hi, unsigned short* __restrict__ wOff_lo)
{
    int blk = blockIdx.x;
    if (blk < 1024) {
        __shared__ float t[64][65];
        int b    = blk >> 8;
        int hw0  = (blk & 255) * 64;
        int lane = (int)(threadIdx.x & 63);
        int w4   = (int)(threadIdx.x >> 6);

        const float* xb = x + b * (Cin * HW) + hw0;
#pragma unroll
        for (int i = 0; i < 16; ++i) {
            int cin = w4 * 16 + i;
            t[cin][lane] = xb[cin * HW + lane];
        }
        __syncthreads();
        unsigned int* dst = xT16 + ((size_t)b * HW + hw0) * 32;
        int px = (int)(threadIdx.x >> 2);
        int c8 = (int)(threadIdx.x & 3) * 8;
#pragma unroll
        for (int i = 0; i < 8; ++i) {
            int cp = c8 + i;
            dst[px * 32 + cp] = f2bf_pk(t[2 * cp][px], t[2 * cp + 1][px]);
        }
    } else {
        int i = (blk - 1024) * 256 + (int)threadIdx.x;
        if (i < 36864) {
            int j = i % 8;  int t = i / 8;
            int l = t % 64; t /= 64;
            int h = t % 2;  t /= 2;
            int w = t % 4;  int k = t / 4;
            int cout = 16 * w + (l & 15);
            int cin  = 32 * h + 8 * (l >> 4) + j;
            float v = weight[cout * 576 + cin * 9 + k];
            unsigned short hi = f2bf(v);
            wA_hi[i] = hi;
            wA_lo[i] = f2bf(v - bf2f(hi));

            int o = cout;
            float vo = o < 27 ? w_off[o * 576 + cin * 9 + k] : 0.f;
            unsigned short oh = f2bf(vo);
            wOff_hi[i] = oh;
            wOff_lo[i] = f2bf(vo - bf2f(oh));
        }
    }
}

// ---------------------------------------------------------------------------
// MERGED deformable conv, LDS-region edition. Block = 63 px of ONE row
// (lane 63 = pad duplicating px 62). Region[32 cp][6 rows][68 cols] staged
// once; phase-0 taps and phase-1 bilinear corners read from region (scalar
// LDS). Per-lane global fallback for |offset| beyond region (never in
// practice, correct always). All MFMA/staging/fragment machinery R13-verbatim.
// ---------------------------------------------------------------------------
__global__ __launch_bounds__(256, 2) void mdcn_kernel(
    const unsigned int* __restrict__ xT16, const float* __restrict__ b_off,
    const unsigned short* __restrict__ wOff_hi,
    const unsigned short* __restrict__ wOff_lo,
    const unsigned short* __restrict__ wA_hi,
    const unsigned short* __restrict__ wA_lo,
    const float* __restrict__ bias, float* __restrict__ out)
{
    __shared__ unsigned int region[32 * RSTR];   // 52.2 KB
    __shared__ unsigned int lds[2][32 * ROWU];   // 17.4 KB staging (dbuf)
    __shared__ float Ap[27][64];                 // 6.9 KB offset-conv output

    int wg   = swz_block(blockIdx.x, NBLK);
    int wid  = __builtin_amdgcn_readfirstlane((int)(threadIdx.x >> 6));
    int lane = (int)(threadIdx.x & 63);
    int b    = wg / 252;
    int rem  = wg - b * 252;
    int ho   = rem >> 1;
    int c0   = (rem & 1) * WOB;
    int x_lo = c0 - 1;
    int pxs  = min(lane, 62);
    int wo   = c0 + pxs;

    const unsigned int* xTb = xT16 + (size_t)b * HW * 32;

    // ===================== region staging (once per block) ==================
    for (int i = 0; i < 13; ++i) {
        int idx4 = (int)threadIdx.x + 256 * i;
        if (idx4 < 3264) {
            int cp4 = (idx4 & 7) * 4;
            int rc  = idx4 >> 3;                 // row*68+col, 0..407
            int row = rc / 68;
            int col = rc - row * 68;
            int y = min(max(ho - 1 + row, 0), Hh - 1);
            int x = min(max(x_lo + col, 0), Ww - 1);
            uint4 q = *reinterpret_cast<const uint4*>(xTb + (y * Ww + x) * 32 + cp4);
            region[(cp4 + 0) * RSTR + rc] = q.x;
            region[(cp4 + 1) * RSTR + rc] = q.y;
            region[(cp4 + 2) * RSTR + rc] = q.z;
            region[(cp4 + 3) * RSTR + rc] = q.w;
        }
    }
    __syncthreads();

    // ======================= phase 0: offset conv ==========================
    {
        unsigned int u[8];
        auto LOADT = [&](int k) {
            int kh = k / 3, kw = k - 3 * kh;
            int off = (kh + 1) * 68 + (pxs + 1 + kw);
#pragma unroll
            for (int j = 0; j < 8; ++j)
                u[j] = region[(wid * 8 + j) * RSTR + off];
        };
        auto WRITE0 = [&](int buf) {
            unsigned int* dst = &lds[buf][(8 * wid) * ROWU + lane];
#pragma unroll
            for (int j = 0; j < 8; ++j) dst[j * ROWU] = u[j];
        };

        int ct = wid & 1;          // cout tile (o 0-15 / 16-31)
        int t0 = (wid >> 1) * 2;   // first px tile
        f32x4 acc0 = {0.f, 0.f, 0.f, 0.f}, acc1 = acc0;

        LOADT(0);
        WRITE0(0);
        __syncthreads();

#pragma unroll
        for (int k = 0; k < 9; ++k) {
            int cur = k & 1;
            if (k < 8) { LOADT(k + 1); WRITE0(cur ^ 1); }
            {
                const bf16x8* waH = reinterpret_cast<const bf16x8*>(
                    wOff_hi + ((k * 4 + ct) * 2) * 512 + lane * 8);
                const bf16x8* waL = reinterpret_cast<const bf16x8*>(
                    wOff_lo + ((k * 4 + ct) * 2) * 512 + lane * 8);
                bf16x8 a0h = waH[0], a1h = waH[64];
                bf16x8 a0l = waL[0], a1l = waL[64];
                const unsigned int* Lh = &lds[cur][0];
                int g4 = (lane >> 4) * 4;
#pragma unroll
                for (int tt = 0; tt < 2; ++tt) {
                    int colp = 16 * (t0 + tt) + (lane & 15);
                    bf16x8 b0 = mk8(Lh[(g4 + 0) * ROWU + colp], Lh[(g4 + 1) * ROWU + colp],
                                    Lh[(g4 + 2) * ROWU + colp], Lh[(g4 + 3) * ROWU + colp]);
                    bf16x8 b1 = mk8(Lh[(16 + g4 + 0) * ROWU + colp], Lh[(16 + g4 + 1) * ROWU + colp],
                                    Lh[(16 + g4 + 2) * ROWU + colp], Lh[(16 + g4 + 3) * ROWU + colp]);
                    f32x4& a = tt ? acc1 : acc0;
                    a = __builtin_amdgcn_mfma_f32_16x16x32_bf16(a0h, b0, a, 0, 0, 0);
                    a = __builtin_amdgcn_mfma_f32_16x16x32_bf16(a0l, b0, a, 0, 0, 0);
                    a = __builtin_amdgcn_mfma_f32_16x16x32_bf16(a1h, b1, a, 0, 0, 0);
                    a = __builtin_amdgcn_mfma_f32_16x16x32_bf16(a1l, b1, a, 0, 0, 0);
                }
            }
            __syncthreads();
        }

#pragma unroll
        for (int tt = 0; tt < 2; ++tt) {
            f32x4 a = tt ? acc1 : acc0;
            int px = 16 * (t0 + tt) + (lane & 15);
#pragma unroll
            for (int rg = 0; rg < 4; ++rg) {
                int o = 16 * ct + 4 * (lane >> 4) + rg;
                if (o < 27) Ap[o][px] = a[rg];
            }
        }
        __syncthreads();
    }

    // ======================= phase 1: sample + main conv ===================
    auto SAMPLE = [&](int k, int buf) {
        float oy = Ap[2 * k][lane];
        float ox = Ap[2 * k + 1][lane];
        float mv = Ap[18 + k][lane] + b_off[18 + k];
        float ys = (float)(ho + k / 3) + oy + b_off[2 * k];
        float xs = (float)(wo + k % 3) + ox + b_off[2 * k + 1];
        float m  = 1.0f / (1.0f + expf(-mv));
        float y0f = floorf(ys), x0f = floorf(xs);
        float wy = ys - y0f, wx = xs - x0f;
        int y0 = (int)y0f, x0 = (int)x0f;
        float vy0 = (y0 >= 0  && y0 < Hh)     ? 1.f : 0.f;
        float vy1 = (y0 >= -1 && y0 < Hh - 1) ? 1.f : 0.f;
        float vx0 = (x0 >= 0  && x0 < Ww)     ? 1.f : 0.f;
        float vx1 = (x0 >= -1 && x0 < Ww - 1) ? 1.f : 0.f;
        float W00 = (1.f - wy) * (1.f - wx) * m * vy0 * vx0;
        float W01 = (1.f - wy) * wx         * m * vy0 * vx1;
        float W10 = wy         * (1.f - wx) * m * vy1 * vx0;
        float W11 = wy         * wx         * m * vy1 * vx1;

        unsigned int cu00[8], cu01[8], cu10[8], cu11[8];
        bool ok = (y0 >= ho - 1) && (y0 <= ho + 3) &&
                  (x0 >= x_lo) && (x0 <= x_lo + 66);
        if (ok) {
            int s00 = (y0 - (ho - 1)) * 68 + (x0 - x_lo);
#pragma unroll
            for (int j = 0; j < 8; ++j) {
                int basej = (wid * 8 + j) * RSTR + s00;
                cu00[j] = region[basej];
                cu01[j] = region[basej + 1];
                cu10[j] = region[basej + 68];
                cu11[j] = region[basej + 69];
            }
        } else {
            // global fallback (R13-exact); essentially never taken
            int y0c = min(max(y0, 0), Hh - 1), y1c = min(max(y0 + 1, 0), Hh - 1);
            int x0c = min(max(x0, 0), Ww - 1), x1c = min(max(x0 + 1, 0), Ww - 1);
            const unsigned int* bw = xTb + wid * 8;
            uint4 qa, qb;
            qa = *reinterpret_cast<const uint4*>(bw + (y0c * Ww + x0c) * 32);
            qb = *reinterpret_cast<const uint4*>(bw + (y0c * Ww + x0c) * 32 + 4);
            cu00[0]=qa.x; cu00[1]=qa.y; cu00[2]=qa.z; cu00[3]=qa.w;
            cu00[4]=qb.x; cu00[5]=qb.y; cu00[6]=qb.z; cu00[7]=qb.w;
            qa = *reinterpret_cast<const uint4*>(bw + (y0c * Ww + x1c) * 32);
            qb = *reinterpret_cast<const uint4*>(bw + (y0c * Ww + x1c) * 32 + 4);
            cu01[0]=qa.x; cu01[1]=qa.y; cu01[2]=qa.z; cu01[3]=qa.w;
            cu01[4]=qb.x; cu01[5]=qb.y; cu01[6]=qb.z; cu01[7]=qb.w;
            qa = *reinterpret_cast<const uint4*>(bw + (y1c * Ww + x0c) * 32);
            qb = *reinterpret_cast<const uint4*>(bw + (y1c * Ww + x0c) * 32 + 4);
            cu10[0]=qa.x; cu10[1]=qa.y; cu10[2]=qa.z; cu10[3]=qa.w;
            cu10[4]=qb.x; cu10[5]=qb.y; cu10[6]=qb.z; cu10[7]=qb.w;
            qa = *reinterpret_cast<const uint4*>(bw + (y1c * Ww + x1c) * 32);
            qb = *reinterpret_cast<const uint4*>(bw + (y1c * Ww + x1c) * 32 + 4);
            cu11[0]=qa.x; cu11[1]=qa.y; cu11[2]=qa.z; cu11[3]=qa.w;
            cu11[4]=qb.x; cu11[5]=qb.y; cu11[6]=qb.z; cu11[7]=qb.w;
        }

        unsigned int* dst = &lds[buf][(8 * wid) * ROWU + lane];
#pragma unroll
        for (int j = 0; j < 8; ++j) {
            float c00a = bf2f((unsigned short)(cu00[j] & 0xffff));
            float c00b = bf2f((unsigned short)(cu00[j] >> 16));
            float c01a = bf2f((unsigned short)(cu01[j] & 0xffff));
            float c01b = bf2f((unsigned short)(cu01[j] >> 16));
            float c10a = bf2f((unsigned short)(cu10[j] & 0xffff));
            float c10b = bf2f((unsigned short)(cu10[j] >> 16));
            float c11a = bf2f((unsigned short)(cu11[j] & 0xffff));
            float c11b = bf2f((unsigned short)(cu11[j] >> 16));
            float s0 = W00 * c00a + W01 * c01a;
            s0 = fmaf(W10, c10a, s0); s0 = fmaf(W11, c11a, s0);
            float s1 = W00 * c00b + W01 * c01b;
            s1 = fmaf(W10, c10b, s1); s1 = fmaf(W11, c11b, s1);
            dst[j * ROWU] = f2bf_pk(s0, s1);
        }
    };

    f32x4 acc[4];
#pragma unroll
    for (int t = 0; t < 4; ++t) acc[t] = {0.f, 0.f, 0.f, 0.f};

    SAMPLE(0, 0);
    __syncthreads();

#pragma unroll
    for (int k = 0; k < 9; ++k) {
        int cur = k & 1;
        if (k < 8) SAMPLE(k + 1, cur ^ 1);
        {
            const bf16x8* waH = reinterpret_cast<const bf16x8*>(
                wA_hi + ((k * 4 + wid) * 2) * 512 + lane * 8);
            const bf16x8* waL = reinterpret_cast<const bf16x8*>(
                wA_lo + ((k * 4 + wid) * 2) * 512 + lane * 8);
            bf16x8 a0h = waH[0], a1h = waH[64];
            bf16x8 a0l = waL[0], a1l = waL[64];
            const unsigned int* Lh = &lds[cur][0];
            int g4 = (lane >> 4) * 4;
#pragma unroll
            for (int t = 0; t < 4; ++t) {
                int colp = 16 * t + (lane & 15);
                bf16x8 b0 = mk8(Lh[(g4 + 0) * ROWU + colp], Lh[(g4 + 1) * ROWU + colp],
                                Lh[(g4 + 2) * ROWU + colp], Lh[(g4 + 3) * ROWU + colp]);
                bf16x8 b1 = mk8(Lh[(16 + g4 + 0) * ROWU + colp], Lh[(16 + g4 + 1) * ROWU + colp],
                                Lh[(16 + g4 + 2) * ROWU + colp], Lh[(16 + g4 + 3) * ROWU + colp]);
                acc[t] = __builtin_amdgcn_mfma_f32_16x16x32_bf16(a0h, b0, acc[t], 0, 0, 0);
                acc[t] = __builtin_amdgcn_mfma_f32_16x16x32_bf16(a0l, b0, acc[t], 0, 0, 0);
                acc[t] = __builtin_amdgcn_mfma_f32_16x16x32_bf16(a1h, b1, acc[t], 0, 0, 0);
                acc[t] = __builtin_amdgcn_mfma_f32_16x16x32_bf16(a1l, b1, acc[t], 0, 0, 0);
            }
        }
        __syncthreads();
    }

#pragma unroll
    for (int t = 0; t < 4; ++t) {
        int ps = 16 * t + (lane & 15);
        if (ps >= WOB) continue;             // skip pad slot 63
        int col = c0 + ps;
#pragma unroll
        for (int rg = 0; rg < 4; ++rg) {
            int cout = 16 * wid + 4 * (lane >> 4) + rg;
            float v = acc[t][rg] + bias[cout];
            out[((b * Cout + cout) * Ho + ho) * Wo + col] = fmaxf(v, 0.f);
        }
    }
}

extern "C" void kernel_launch(void* const* d_in, const int* in_sizes, int n_in,
                              void* d_out, int out_size, void* d_ws, size_t ws_size,
                              hipStream_t stream)
{
    const float* x      = (const float*)d_in[0];
    const float* w_off  = (const float*)d_in[1];
    const float* b_off  = (const float*)d_in[2];
    const float* weight = (const float*)d_in[3];
    const float* bias   = (const float*)d_in[4];

    unsigned int* xT16 = (unsigned int*)d_ws;                   // Bn*HW*32 uints
    unsigned short* wA_hi   = (unsigned short*)(xT16 + (size_t)Bn * HW * 32);
    unsigned short* wA_lo   = wA_hi + 36864;
    unsigned short* wOff_hi = wA_lo + 36864;
    unsigned short* wOff_lo = wOff_hi + 36864;

    prep_transpose_kernel<<<1024 + 144, 256, 0, stream>>>(
        x, w_off, weight, xT16, wA_hi, wA_lo, wOff_hi, wOff_lo);
    mdcn_kernel<<<NBLK, 256, 0, stream>>>(xT16, b_off, wOff_hi, wOff_lo,
                                          wA_hi, wA_lo, bias, (float*)d_out);
}

// Round 15
// 53.007 us; speedup vs baseline: 1.4518x; 1.0759x over previous
//
#include <hip/hip_runtime.h>
#include <hip/hip_bf16.h>
#include <math.h>

namespace {
constexpr int Bn = 4, Cin = 64, Cout = 64, Hh = 128, Ww = 128, Ho = 126, Wo = 126;
constexpr int HW = Hh * Ww;                 // 16384
constexpr int WOB = 63;                     // pixels per block (row-aligned)
constexpr int NBLK = Bn * Ho * 2;           // 1008 blocks (63 px each, exact)
constexpr int ROWU = 68;                    // staging row stride (uints): 64+4 pad
constexpr int RSTR = 346;                   // region stride per cp: 5*68=340 + 6 pad
                                            // (RSTR % 8 == 2 -> 4*RSTR % 32 == 8:
                                            //  conflict-free cp-strided access)
}

typedef __attribute__((ext_vector_type(8))) short bf16x8;
typedef __attribute__((ext_vector_type(4))) float f32x4;

__device__ __forceinline__ unsigned short f2bf(float f) {
    __hip_bfloat16 h = __float2bfloat16(f);
    return __builtin_bit_cast(unsigned short, h);
}
__device__ __forceinline__ float bf2f(unsigned short u) {
    unsigned int v = (unsigned int)u << 16;
    return __builtin_bit_cast(float, v);
}
__device__ __forceinline__ unsigned int f2bf_pk(float lo, float hi) {
    return (unsigned int)f2bf(lo) | ((unsigned int)f2bf(hi) << 16);
}
__device__ __forceinline__ bf16x8 mk8(unsigned int u0, unsigned int u1,
                                      unsigned int u2, unsigned int u3) {
    union { unsigned int u[4]; bf16x8 v; } x;
    x.u[0] = u0; x.u[1] = u1; x.u[2] = u2; x.u[3] = u3;
    return x.v;
}
// bijective XCD swizzle (m204): contiguous chunk of blocks per XCD
__device__ __forceinline__ int swz_block(int orig, int nwg) {
    int q = nwg >> 3, r = nwg & 7;
    int xcd = orig & 7, idx = orig >> 3;
    return (xcd < r ? xcd * (q + 1) : r * (q + 1) + (xcd - r) * q) + idx;
}

// ---------------------------------------------------------------------------
// prep + transpose merged (R13-proven). Blocks [0,1024): NCHW f32 -> NHWC
// bf16-packed. Blocks [1024,1168): weight A-fragment prep (PROVEN mapping).
// ---------------------------------------------------------------------------
__global__ __launch_bounds__(256) void prep_transpose_kernel(
    const float* __restrict__ x, const float* __restrict__ w_off,
    const float* __restrict__ weight, unsigned int* __restrict__ xT16,
    unsigned short* __restrict__ wA_hi, unsigned short* __restrict__ wA_lo,
    unsigned short* __restrict__ wOff_hi, unsigned short* __restrict__ wOff_lo)
{
    int blk = blockIdx.x;
    if (blk < 1024) {
        __shared__ float t[64][65];
        int b    = blk >> 8;
        int hw0  = (blk & 255) * 64;
        int lane = (int)(threadIdx.x & 63);
        int w4   = (int)(threadIdx.x >> 6);

        const float* xb = x + b * (Cin * HW) + hw0;
#pragma unroll
        for (int i = 0; i < 16; ++i) {
            int cin = w4 * 16 + i;
            t[cin][lane] = xb[cin * HW + lane];
        }
        __syncthreads();
        unsigned int* dst = xT16 + ((size_t)b * HW + hw0) * 32;
        int px = (int)(threadIdx.x >> 2);
        int c8 = (int)(threadIdx.x & 3) * 8;
#pragma unroll
        for (int i = 0; i < 8; ++i) {
            int cp = c8 + i;
            dst[px * 32 + cp] = f2bf_pk(t[2 * cp][px], t[2 * cp + 1][px]);
        }
    } else {
        int i = (blk - 1024) * 256 + (int)threadIdx.x;
        if (i < 36864) {
            int j = i % 8;  int t = i / 8;
            int l = t % 64; t /= 64;
            int h = t % 2;  t /= 2;
            int w = t % 4;  int k = t / 4;
            int cout = 16 * w + (l & 15);
            int cin  = 32 * h + 8 * (l >> 4) + j;
            float v = weight[cout * 576 + cin * 9 + k];
            unsigned short hi = f2bf(v);
            wA_hi[i] = hi;
            wA_lo[i] = f2bf(v - bf2f(hi));

            int o = cout;
            float vo = o < 27 ? w_off[o * 576 + cin * 9 + k] : 0.f;
            unsigned short oh = f2bf(vo);
            wOff_hi[i] = oh;
            wOff_lo[i] = f2bf(vo - bf2f(oh));
        }
    }
}

// ---------------------------------------------------------------------------
// MERGED deformable conv, direct-region edition. Block = 63 px of ONE row.
// Region[32 cp][5 rows][68 cols] staged once (conflict-free RSTR).
// Phase 0: offset conv reads B-fragments DIRECTLY from region (no staging,
// no per-k barriers) -> Ap[27][64]. Phase 1: R14-proven sample + main conv.
// Scalar-uint LDS only (session rule).
// ---------------------------------------------------------------------------
__global__ __launch_bounds__(256, 2) void mdcn_kernel(
    const unsigned int* __restrict__ xT16, const float* __restrict__ b_off,
    const unsigned short* __restrict__ wOff_hi,
    const unsigned short* __restrict__ wOff_lo,
    const unsigned short* __restrict__ wA_hi,
    const unsigned short* __restrict__ wA_lo,
    const float* __restrict__ bias, float* __restrict__ out)
{
    __shared__ unsigned int region[32 * RSTR];   // 44.3 KB
    __shared__ unsigned int lds[2][32 * ROWU];   // 17.4 KB staging (dbuf)
    __shared__ float Ap[27][64];                 // 6.9 KB offset-conv output

    int wg   = swz_block(blockIdx.x, NBLK);
    int wid  = __builtin_amdgcn_readfirstlane((int)(threadIdx.x >> 6));
    int lane = (int)(threadIdx.x & 63);
    int b    = wg / 252;
    int rem  = wg - b * 252;
    int ho   = rem >> 1;
    int c0   = (rem & 1) * WOB;
    int x_lo = c0 - 1;
    int pxs  = min(lane, 62);
    int wo   = c0 + pxs;

    const unsigned int* xTb = xT16 + (size_t)b * HW * 32;

    // ===================== region staging (once per block) ==================
    // rows 0..4 = image rows ho-1 .. ho+3 (clamped), cols 0..67 = x_lo..x_lo+67
    for (int i = 0; i < 11; ++i) {
        int idx4 = (int)threadIdx.x + 256 * i;
        if (idx4 < 2720) {
            int cp4 = (idx4 & 7) * 4;
            int rc  = idx4 >> 3;                 // row*68+col, 0..339
            int row = rc / 68;
            int col = rc - row * 68;
            int y = min(max(ho - 1 + row, 0), Hh - 1);
            int x = min(max(x_lo + col, 0), Ww - 1);
            uint4 q = *reinterpret_cast<const uint4*>(xTb + (y * Ww + x) * 32 + cp4);
            region[(cp4 + 0) * RSTR + rc] = q.x;
            region[(cp4 + 1) * RSTR + rc] = q.y;
            region[(cp4 + 2) * RSTR + rc] = q.z;
            region[(cp4 + 3) * RSTR + rc] = q.w;
        }
    }
    __syncthreads();

    // ======================= phase 0: offset conv ==========================
    // B-fragments read directly from region; no staging, no inner barriers.
    {
        int ct = wid & 1;          // cout tile (o 0-15 / 16-31)
        int t0 = (wid >> 1) * 2;   // first px tile
        f32x4 acc0 = {0.f, 0.f, 0.f, 0.f}, acc1 = acc0;
        int g4 = (lane >> 4) * 4;

#pragma unroll
        for (int k = 0; k < 9; ++k) {
            int kh = k / 3, kw = k - 3 * kh;
            int roff = (kh + 1) * 68 + 1 + kw;   // + px -> region col index
            const bf16x8* waH = reinterpret_cast<const bf16x8*>(
                wOff_hi + ((k * 4 + ct) * 2) * 512 + lane * 8);
            const bf16x8* waL = reinterpret_cast<const bf16x8*>(
                wOff_lo + ((k * 4 + ct) * 2) * 512 + lane * 8);
            bf16x8 a0h = waH[0], a1h = waH[64];
            bf16x8 a0l = waL[0], a1l = waL[64];
#pragma unroll
            for (int tt = 0; tt < 2; ++tt) {
                int px = 16 * (t0 + tt) + (lane & 15);
                int ci = roff + px;
                bf16x8 b0 = mk8(region[(g4 + 0) * RSTR + ci], region[(g4 + 1) * RSTR + ci],
                                region[(g4 + 2) * RSTR + ci], region[(g4 + 3) * RSTR + ci]);
                bf16x8 b1 = mk8(region[(16 + g4 + 0) * RSTR + ci], region[(16 + g4 + 1) * RSTR + ci],
                                region[(16 + g4 + 2) * RSTR + ci], region[(16 + g4 + 3) * RSTR + ci]);
                f32x4& a = tt ? acc1 : acc0;
                a = __builtin_amdgcn_mfma_f32_16x16x32_bf16(a0h, b0, a, 0, 0, 0);
                a = __builtin_amdgcn_mfma_f32_16x16x32_bf16(a0l, b0, a, 0, 0, 0);
                a = __builtin_amdgcn_mfma_f32_16x16x32_bf16(a1h, b1, a, 0, 0, 0);
                a = __builtin_amdgcn_mfma_f32_16x16x32_bf16(a1l, b1, a, 0, 0, 0);
            }
        }

#pragma unroll
        for (int tt = 0; tt < 2; ++tt) {
            f32x4 a = tt ? acc1 : acc0;
            int px = 16 * (t0 + tt) + (lane & 15);
#pragma unroll
            for (int rg = 0; rg < 4; ++rg) {
                int o = 16 * ct + 4 * (lane >> 4) + rg;
                if (o < 27) Ap[o][px] = a[rg];
            }
        }
        __syncthreads();
    }

    // ======================= phase 1: sample + main conv ===================
    auto SAMPLE = [&](int k, int buf) {
        float oy = Ap[2 * k][lane];
        float ox = Ap[2 * k + 1][lane];
        float mv = Ap[18 + k][lane] + b_off[18 + k];
        float ys = (float)(ho + k / 3) + oy + b_off[2 * k];
        float xs = (float)(wo + k % 3) + ox + b_off[2 * k + 1];
        float m  = 1.0f / (1.0f + expf(-mv));
        float y0f = floorf(ys), x0f = floorf(xs);
        float wy = ys - y0f, wx = xs - x0f;
        int y0 = (int)y0f, x0 = (int)x0f;
        float vy0 = (y0 >= 0  && y0 < Hh)     ? 1.f : 0.f;
        float vy1 = (y0 >= -1 && y0 < Hh - 1) ? 1.f : 0.f;
        float vx0 = (x0 >= 0  && x0 < Ww)     ? 1.f : 0.f;
        float vx1 = (x0 >= -1 && x0 < Ww - 1) ? 1.f : 0.f;
        float W00 = (1.f - wy) * (1.f - wx) * m * vy0 * vx0;
        float W01 = (1.f - wy) * wx         * m * vy0 * vx1;
        float W10 = wy         * (1.f - wx) * m * vy1 * vx0;
        float W11 = wy         * wx         * m * vy1 * vx1;

        unsigned int cu00[8], cu01[8], cu10[8], cu11[8];
        bool ok = (y0 >= ho - 1) && (y0 <= ho + 2) &&
                  (x0 >= x_lo) && (x0 <= x_lo + 66);
        if (ok) {
            int s00 = (y0 - (ho - 1)) * 68 + (x0 - x_lo);
#pragma unroll
            for (int j = 0; j < 8; ++j) {
                int basej = (wid * 8 + j) * RSTR + s00;
                cu00[j] = region[basej];
                cu01[j] = region[basej + 1];
                cu10[j] = region[basej + 68];
                cu11[j] = region[basej + 69];
            }
        } else {
            // global fallback (R13-exact); essentially never taken
            int y0c = min(max(y0, 0), Hh - 1), y1c = min(max(y0 + 1, 0), Hh - 1);
            int x0c = min(max(x0, 0), Ww - 1), x1c = min(max(x0 + 1, 0), Ww - 1);
            const unsigned int* bw = xTb + wid * 8;
            uint4 qa, qb;
            qa = *reinterpret_cast<const uint4*>(bw + (y0c * Ww + x0c) * 32);
            qb = *reinterpret_cast<const uint4*>(bw + (y0c * Ww + x0c) * 32 + 4);
            cu00[0]=qa.x; cu00[1]=qa.y; cu00[2]=qa.z; cu00[3]=qa.w;
            cu00[4]=qb.x; cu00[5]=qb.y; cu00[6]=qb.z; cu00[7]=qb.w;
            qa = *reinterpret_cast<const uint4*>(bw + (y0c * Ww + x1c) * 32);
            qb = *reinterpret_cast<const uint4*>(bw + (y0c * Ww + x1c) * 32 + 4);
            cu01[0]=qa.x; cu01[1]=qa.y; cu01[2]=qa.z; cu01[3]=qa.w;
            cu01[4]=qb.x; cu01[5]=qb.y; cu01[6]=qb.z; cu01[7]=qb.w;
            qa = *reinterpret_cast<const uint4*>(bw + (y1c * Ww + x0c) * 32);
            qb = *reinterpret_cast<const uint4*>(bw + (y1c * Ww + x0c) * 32 + 4);
            cu10[0]=qa.x; cu10[1]=qa.y; cu10[2]=qa.z; cu10[3]=qa.w;
            cu10[4]=qb.x; cu10[5]=qb.y; cu10[6]=qb.z; cu10[7]=qb.w;
            qa = *reinterpret_cast<const uint4*>(bw + (y1c * Ww + x1c) * 32);
            qb = *reinterpret_cast<const uint4*>(bw + (y1c * Ww + x1c) * 32 + 4);
            cu11[0]=qa.x; cu11[1]=qa.y; cu11[2]=qa.z; cu11[3]=qa.w;
            cu11[4]=qb.x; cu11[5]=qb.y; cu11[6]=qb.z; cu11[7]=qb.w;
        }

        unsigned int* dst = &lds[buf][(8 * wid) * ROWU + lane];
#pragma unroll
        for (int j = 0; j < 8; ++j) {
            float c00a = bf2f((unsigned short)(cu00[j] & 0xffff));
            float c00b = bf2f((unsigned short)(cu00[j] >> 16));
            float c01a = bf2f((unsigned short)(cu01[j] & 0xffff));
            float c01b = bf2f((unsigned short)(cu01[j] >> 16));
            float c10a = bf2f((unsigned short)(cu10[j] & 0xffff));
            float c10b = bf2f((unsigned short)(cu10[j] >> 16));
            float c11a = bf2f((unsigned short)(cu11[j] & 0xffff));
            float c11b = bf2f((unsigned short)(cu11[j] >> 16));
            float s0 = W00 * c00a + W01 * c01a;
            s0 = fmaf(W10, c10a, s0); s0 = fmaf(W11, c11a, s0);
            float s1 = W00 * c00b + W01 * c01b;
            s1 = fmaf(W10, c10b, s1); s1 = fmaf(W11, c11b, s1);
            dst[j * ROWU] = f2bf_pk(s0, s1);
        }
    };

    f32x4 acc[4];
#pragma unroll
    for (int t = 0; t < 4; ++t) acc[t] = {0.f, 0.f, 0.f, 0.f};

    SAMPLE(0, 0);
    __syncthreads();

#pragma unroll
    for (int k = 0; k < 9; ++k) {
        int cur = k & 1;
        if (k < 8) SAMPLE(k + 1, cur ^ 1);
        {
            const bf16x8* waH = reinterpret_cast<const bf16x8*>(
                wA_hi + ((k * 4 + wid) * 2) * 512 + lane * 8);
            const bf16x8* waL = reinterpret_cast<const bf16x8*>(
                wA_lo + ((k * 4 + wid) * 2) * 512 + lane * 8);
            bf16x8 a0h = waH[0], a1h = waH[64];
            bf16x8 a0l = waL[0], a1l = waL[64];
            const unsigned int* Lh = &lds[cur][0];
            int g4 = (lane >> 4) * 4;
#pragma unroll
            for (int t = 0; t < 4; ++t) {
                int colp = 16 * t + (lane & 15);
                bf16x8 b0 = mk8(Lh[(g4 + 0) * ROWU + colp], Lh[(g4 + 1) * ROWU + colp],
                                Lh[(g4 + 2) * ROWU + colp], Lh[(g4 + 3) * ROWU + colp]);
                bf16x8 b1 = mk8(Lh[(16 + g4 + 0) * ROWU + colp], Lh[(16 + g4 + 1) * ROWU + colp],
                                Lh[(16 + g4 + 2) * ROWU + colp], Lh[(16 + g4 + 3) * ROWU + colp]);
                acc[t] = __builtin_amdgcn_mfma_f32_16x16x32_bf16(a0h, b0, acc[t], 0, 0, 0);
                acc[t] = __builtin_amdgcn_mfma_f32_16x16x32_bf16(a0l, b0, acc[t], 0, 0, 0);
                acc[t] = __builtin_amdgcn_mfma_f32_16x16x32_bf16(a1h, b1, acc[t], 0, 0, 0);
                acc[t] = __builtin_amdgcn_mfma_f32_16x16x32_bf16(a1l, b1, acc[t], 0, 0, 0);
            }
        }
        __syncthreads();
    }

#pragma unroll
    for (int t = 0; t < 4; ++t) {
        int ps = 16 * t + (lane & 15);
        if (ps >= WOB) continue;             // skip pad slot 63
        int col = c0 + ps;
#pragma unroll
        for (int rg = 0; rg < 4; ++rg) {
            int cout = 16 * wid + 4 * (lane >> 4) + rg;
            float v = acc[t][rg] + bias[cout];
            out[((b * Cout + cout) * Ho + ho) * Wo + col] = fmaxf(v, 0.f);
        }
    }
}

extern "C" void kernel_launch(void* const* d_in, const int* in_sizes, int n_in,
                              void* d_out, int out_size, void* d_ws, size_t ws_size,
                              hipStream_t stream)
{
    const float* x      = (const float*)d_in[0];
    const float* w_off  = (const float*)d_in[1];
    const float* b_off  = (const float*)d_in[2];
    const float* weight = (const float*)d_in[3];
    const float* bias   = (const float*)d_in[4];

    unsigned int* xT16 = (unsigned int*)d_ws;                   // Bn*HW*32 uints
    unsigned short* wA_hi   = (unsigned short*)(xT16 + (size_t)Bn * HW * 32);
    unsigned short* wA_lo   = wA_hi + 36864;
    unsigned short* wOff_hi = wA_lo + 36864;
    unsigned short* wOff_lo = wOff_hi + 36864;

    prep_transpose_kernel<<<1024 + 144, 256, 0, stream>>>(
        x, w_off, weight, xT16, wA_hi, wA_lo, wOff_hi, wOff_lo);
    mdcn_kernel<<<NBLK, 256, 0, stream>>>(xT16, b_off, wOff_hi, wOff_lo,
                                          wA_hi, wA_lo, bias, (float*)d_out);
}